// Round 4
// baseline (553.274 us; speedup 1.0000x reference)
//
#include <hip/hip_runtime.h>
#include <hip/hip_bf16.h>
#include <cstdio>

// LoRALinear: out[M,N] = x[M,K] @ W[N,K]^T + bias, W = base + (16/8)*(lora_B @ lora_A)
// M=8192, N=4096, K=4096 (fp32 in/out; internal bf16 MFMA).
// R8: R7 falsified latency-depth (279us, MfmaUtil 43.7%). Cycle model: per phase,
// MFMA pipe = 2 waves/SIMD x 16 MFMA x ~19.4cy = 621cy, measured phase = ~1308cy ->
// ~687cy/phase is barrier/drain overhead (8 barriers/tile, 1 block/CU, 2 waves/SIMD).
// Fix: collapse 4 phases -> 2 regions/tile (2 barriers/tile). Within a region: issue
// all 12 ds_reads + STAGE, then lgkmcnt(4) -> 16 MFMA -> lgkmcnt(0) -> 16 MFMA.
// vmcnt ledger unchanged from R7 (8/8 steady; 0/4 tail). Final barrier dropped.
// Prep: fused into ONE launch (block-range split; x-path blocks 0..2047, w-path rest).

using bf16   = __bf16;
using bf16x8 = __attribute__((ext_vector_type(8))) __bf16;
using f32x4  = __attribute__((ext_vector_type(4))) float;

#define BM 256
#define BN 256
#define BK 64   // two K-slabs of 32
#define WXBLK 2048

// ---------------- kernel 1: fused prep (x-convert || W-build) ----------------
__global__ __launch_bounds__(256) void prep_fused(
    const float* __restrict__ x, const float* __restrict__ base,
    const float* __restrict__ A, const float* __restrict__ Bm,
    bf16* __restrict__ Xb, bf16* __restrict__ Wb,
    long n8x, int K, int rank, float scale) {
    if (blockIdx.x < WXBLK) {
        // ---- x fp32 -> bf16 stream ----
        const long stride = (long)WXBLK * 256;
        for (long i = (long)blockIdx.x * 256 + threadIdx.x; i < n8x; i += stride) {
            const float4 a = reinterpret_cast<const float4*>(x)[2 * i];
            const float4 b = reinterpret_cast<const float4*>(x)[2 * i + 1];
            bf16x8 o;
            o[0] = (bf16)a.x; o[1] = (bf16)a.y; o[2] = (bf16)a.z; o[3] = (bf16)a.w;
            o[4] = (bf16)b.x; o[5] = (bf16)b.y; o[6] = (bf16)b.z; o[7] = (bf16)b.w;
            reinterpret_cast<bf16x8*>(Xb)[i] = o;
        }
    } else {
        // ---- W row build: one block per output row ----
        const int o = blockIdx.x - WXBLK;
        float br[8];
        const int rr = rank < 8 ? rank : 8;
        for (int r = 0; r < rr; ++r) br[r] = scale * Bm[(size_t)o * rank + r];

        const float* brow = base + (size_t)o * K;
        bf16*        wrow = Wb + (size_t)o * K;

        for (int c = threadIdx.x * 8; c < K; c += 256 * 8) {
            float4 s0 = *reinterpret_cast<const float4*>(brow + c);
            float4 s1 = *reinterpret_cast<const float4*>(brow + c + 4);
            if (rank == 8) {
#pragma unroll
                for (int r = 0; r < 8; ++r) {
                    const float4 a0 = *reinterpret_cast<const float4*>(A + (size_t)r * K + c);
                    const float4 a1 = *reinterpret_cast<const float4*>(A + (size_t)r * K + c + 4);
                    s0.x += br[r] * a0.x; s0.y += br[r] * a0.y;
                    s0.z += br[r] * a0.z; s0.w += br[r] * a0.w;
                    s1.x += br[r] * a1.x; s1.y += br[r] * a1.y;
                    s1.z += br[r] * a1.z; s1.w += br[r] * a1.w;
                }
            } else {
                for (int r = 0; r < rank; ++r) {
                    const float b = scale * Bm[(size_t)o * rank + r];
                    const float4 a0 = *reinterpret_cast<const float4*>(A + (size_t)r * K + c);
                    const float4 a1 = *reinterpret_cast<const float4*>(A + (size_t)r * K + c + 4);
                    s0.x += b * a0.x; s0.y += b * a0.y; s0.z += b * a0.z; s0.w += b * a0.w;
                    s1.x += b * a1.x; s1.y += b * a1.y; s1.z += b * a1.z; s1.w += b * a1.w;
                }
            }
            bf16x8 ov;
            ov[0] = (bf16)s0.x; ov[1] = (bf16)s0.y; ov[2] = (bf16)s0.z; ov[3] = (bf16)s0.w;
            ov[4] = (bf16)s1.x; ov[5] = (bf16)s1.y; ov[6] = (bf16)s1.z; ov[7] = (bf16)s1.w;
            *reinterpret_cast<bf16x8*>(wrow + c) = ov;
        }
    }
}

// ---------------- kernel 2: 256x256 2-region bf16 GEMM, deep-pipelined ----------------
// LDS per matrix: [2 buf][2 kslab][256 rows][32 elems]; slab = 16KiB, staged by
// 2 global_load_lds x 16B per thread (linear dest). Swizzle: 16B chunk c of row r
// lives at slot c^((r>>1)&3) (source pre-swizzled). 8 waves 2Mx4N; per-wave C 128x64.
// Per tile: regionA (slab0): 12 ds_read + STAGE (t+1).s1->nxt + 2x16 MFMA + vmcnt + bar;
//           regionB (slab1): 12 ds_read + STAGE (t+2).s0->cur + 2x16 MFMA + vmcnt + bar.
__global__ __launch_bounds__(512, 2) void gemm_2reg(
    const bf16* __restrict__ Xb,    // [M,K] row-major
    const bf16* __restrict__ Wb,    // [N,K] row-major
    const float* __restrict__ bias, // [N]
    float* __restrict__ out,        // [M,N] row-major fp32
    int M, int N, int K)
{
    __shared__ __align__(16) bf16 As[2 * 2 * 256 * 32];  // 64 KiB
    __shared__ __align__(16) bf16 Bs[2 * 2 * 256 * 32];  // 64 KiB

    const int tid  = threadIdx.x;     // 0..511
    const int lane = tid & 63;
    const int wv   = tid >> 6;        // wave 0..7
    const int wm   = wv >> 2;         // 0..1
    const int wn   = wv & 3;          // 0..3

    // ---- XCD-aware bijective block swizzle (T1): nwg=512, 512%8==0 ----
    const int nbx = gridDim.x;
    const int nwg = gridDim.x * gridDim.y;
    const int orig = blockIdx.y * nbx + blockIdx.x;
    const int swz = ((nwg & 7) == 0) ? ((orig & 7) * (nwg >> 3) + (orig >> 3)) : orig;
    const int m0 = (swz / nbx) * BM;
    const int n0 = (swz % nbx) * BN;

    const int r16 = lane & 15;        // row-in-16 for frags; col for C/D
    const int q   = lane >> 4;        // quad 0..3 -> K-chunk within slab
    const int cq  = (q ^ ((r16 >> 1) & 3)) * 8;  // swizzled elem offset in 32-wide row

    // ---- staging: slot(i)=i*512+tid; row=slot>>2; src chunk c = (tid&3)^((row>>1)&3)
    const bf16* srcA[2];
    const bf16* srcB[2];
#pragma unroll
    for (int i = 0; i < 2; ++i) {
        const int slot = i * 512 + tid;
        const int row  = slot >> 2;
        const int c    = (tid & 3) ^ ((row >> 1) & 3);
        srcA[i] = Xb + (size_t)(m0 + row) * K + c * 8;
        srcB[i] = Wb + (size_t)(n0 + row) * K + c * 8;
    }
    // wave-uniform LDS dest element offsets (within a slab)
    const int dst0 = (0 * 512 + wv * 64) * 8;
    const int dst1 = (1 * 512 + wv * 64) * 8;

#define STAGE_A(buf, kh, koff)                                                        \
    do {                                                                              \
        __builtin_amdgcn_global_load_lds(                                             \
            (const __attribute__((address_space(1))) void*)(srcA[0] + (koff) + (kh) * 32), \
            (__attribute__((address_space(3))) void*)(As + (buf) * 16384 + (kh) * 8192 + dst0), \
            16, 0, 0);                                                                \
        __builtin_amdgcn_global_load_lds(                                             \
            (const __attribute__((address_space(1))) void*)(srcA[1] + (koff) + (kh) * 32), \
            (__attribute__((address_space(3))) void*)(As + (buf) * 16384 + (kh) * 8192 + dst1), \
            16, 0, 0);                                                                \
    } while (0)
#define STAGE_B(buf, kh, koff)                                                        \
    do {                                                                              \
        __builtin_amdgcn_global_load_lds(                                             \
            (const __attribute__((address_space(1))) void*)(srcB[0] + (koff) + (kh) * 32), \
            (__attribute__((address_space(3))) void*)(Bs + (buf) * 16384 + (kh) * 8192 + dst0), \
            16, 0, 0);                                                                \
        __builtin_amdgcn_global_load_lds(                                             \
            (const __attribute__((address_space(1))) void*)(srcB[1] + (koff) + (kh) * 32), \
            (__attribute__((address_space(3))) void*)(Bs + (buf) * 16384 + (kh) * 8192 + dst1), \
            16, 0, 0);                                                                \
    } while (0)

    // ---- k-invariant fragment element offsets (within a slab) ----
    int aoff[2][4], boff[4];
#pragma unroll
    for (int mh = 0; mh < 2; ++mh)
#pragma unroll
        for (int f = 0; f < 4; ++f)
            aoff[mh][f] = (wm * 128 + mh * 64 + f * 16 + r16) * 32 + cq;
#pragma unroll
    for (int f = 0; f < 4; ++f)
        boff[f] = (wn * 64 + f * 16 + r16) * 32 + cq;

    f32x4 acc[8][4] = {};

    const int NT = K / BK;

    // ---- prologue: t0 fully + t1.s0; vmcnt(8) leaves {t0.s1, t1.s0} in flight ----
    STAGE_A(0, 0, 0);
    STAGE_B(0, 0, 0);
    STAGE_A(0, 1, 0);
    STAGE_B(0, 1, 0);
    if (NT > 1) {
        STAGE_A(1, 0, BK);
        STAGE_B(1, 0, BK);
        asm volatile("s_waitcnt vmcnt(8)" ::: "memory");
    } else {
        asm volatile("s_waitcnt vmcnt(4)" ::: "memory");
    }
    __builtin_amdgcn_s_barrier();

    for (int t = 0; t < NT; ++t) {
        const int cur   = t & 1;
        const int nxt   = cur ^ 1;
        const int koff1 = (t + 1) * BK;
        const int koff2 = (t + 2) * BK;
        const bool pre1 = (t + 1 < NT);
        const bool pre2 = (t + 2 < NT);
        bf16x8 bf[4], af0[4], af1[4];

        // ================= region A: slab 0 =================
        {
            const bf16* Ab = As + cur * 16384;
            const bf16* Bb = Bs + cur * 16384;
#pragma unroll
            for (int f = 0; f < 4; ++f) bf[f]  = *reinterpret_cast<const bf16x8*>(Bb + boff[f]);
#pragma unroll
            for (int f = 0; f < 4; ++f) af0[f] = *reinterpret_cast<const bf16x8*>(Ab + aoff[0][f]);
#pragma unroll
            for (int f = 0; f < 4; ++f) af1[f] = *reinterpret_cast<const bf16x8*>(Ab + aoff[1][f]);
            if (pre1) { STAGE_A(nxt, 1, koff1); STAGE_B(nxt, 1, koff1); }  // (t+1).s1
            asm volatile("s_waitcnt lgkmcnt(4)" ::: "memory");             // bf+af0 landed
            __builtin_amdgcn_sched_barrier(0);
            __builtin_amdgcn_s_setprio(1);
#pragma unroll
            for (int f = 0; f < 4; ++f)
#pragma unroll
                for (int n = 0; n < 4; ++n)
                    acc[f][n] = __builtin_amdgcn_mfma_f32_16x16x32_bf16(af0[f], bf[n], acc[f][n], 0, 0, 0);
            __builtin_amdgcn_s_setprio(0);
            asm volatile("s_waitcnt lgkmcnt(0)" ::: "memory");             // af1 landed
            __builtin_amdgcn_sched_barrier(0);
            __builtin_amdgcn_s_setprio(1);
#pragma unroll
            for (int f = 0; f < 4; ++f)
#pragma unroll
                for (int n = 0; n < 4; ++n)
                    acc[4 + f][n] = __builtin_amdgcn_mfma_f32_16x16x32_bf16(af1[f], bf[n], acc[4 + f][n], 0, 0, 0);
            __builtin_amdgcn_s_setprio(0);
            // cur.s1 must be landed for region B; also releases cur.s0 for regB's STAGE.
            if (t == NT - 1) asm volatile("s_waitcnt vmcnt(0)" ::: "memory");
            else             asm volatile("s_waitcnt vmcnt(8)" ::: "memory");
            __builtin_amdgcn_s_barrier();
        }
        // ================= region B: slab 1 =================
        {
            const bf16* Ab = As + cur * 16384 + 8192;
            const bf16* Bb = Bs + cur * 16384 + 8192;
#pragma unroll
            for (int f = 0; f < 4; ++f) bf[f]  = *reinterpret_cast<const bf16x8*>(Bb + boff[f]);
#pragma unroll
            for (int f = 0; f < 4; ++f) af0[f] = *reinterpret_cast<const bf16x8*>(Ab + aoff[0][f]);
#pragma unroll
            for (int f = 0; f < 4; ++f) af1[f] = *reinterpret_cast<const bf16x8*>(Ab + aoff[1][f]);
            if (pre2) { STAGE_A(cur, 0, koff2); STAGE_B(cur, 0, koff2); }  // (t+2).s0 -> released cur.s0
            asm volatile("s_waitcnt lgkmcnt(4)" ::: "memory");
            __builtin_amdgcn_sched_barrier(0);
            __builtin_amdgcn_s_setprio(1);
#pragma unroll
            for (int f = 0; f < 4; ++f)
#pragma unroll
                for (int n = 0; n < 4; ++n)
                    acc[f][n] = __builtin_amdgcn_mfma_f32_16x16x32_bf16(af0[f], bf[n], acc[f][n], 0, 0, 0);
            __builtin_amdgcn_s_setprio(0);
            asm volatile("s_waitcnt lgkmcnt(0)" ::: "memory");
            __builtin_amdgcn_sched_barrier(0);
            __builtin_amdgcn_s_setprio(1);
#pragma unroll
            for (int f = 0; f < 4; ++f)
#pragma unroll
                for (int n = 0; n < 4; ++n)
                    acc[4 + f][n] = __builtin_amdgcn_mfma_f32_16x16x32_bf16(af1[f], bf[n], acc[4 + f][n], 0, 0, 0);
            __builtin_amdgcn_s_setprio(0);
            // (t+1).s0 must be landed for next tile's region A.
            if (t == NT - 2)     asm volatile("s_waitcnt vmcnt(4)" ::: "memory");
            else if (t < NT - 2) asm volatile("s_waitcnt vmcnt(8)" ::: "memory");
            // t == NT-1: nothing left to protect.
            if (t < NT - 1) __builtin_amdgcn_s_barrier();   // epilogue is register-only
        }
    }

    // ---- epilogue: C/D layout col=lane&15, row=q*4+r; add bias; fp32 store ----
#pragma unroll
    for (int mf = 0; mf < 8; ++mf) {
        const int gr = m0 + wm * 128 + (mf >> 2) * 64 + (mf & 3) * 16 + q * 4;
#pragma unroll
        for (int nf = 0; nf < 4; ++nf) {
            const int gc = n0 + wn * 64 + nf * 16 + r16;
            const float bv = bias[gc];
#pragma unroll
            for (int r = 0; r < 4; ++r)
                out[(size_t)(gr + r) * N + gc] = acc[mf][nf][r] + bv;
        }
    }
#undef STAGE_A
#undef STAGE_B
}

extern "C" void kernel_launch(void* const* d_in, const int* in_sizes, int n_in,
                              void* d_out, int out_size, void* d_ws, size_t ws_size,
                              hipStream_t stream) {
    const float* x    = (const float*)d_in[0];
    const float* base = (const float*)d_in[1];
    const float* lA   = (const float*)d_in[2];
    const float* lB   = (const float*)d_in[3];
    const float* bias = (const float*)d_in[4];
    float* out = (float*)d_out;

    const int  N    = in_sizes[4];             // d_out = 4096
    const int  rank = in_sizes[3] / N;         // 8
    const int  K    = in_sizes[2] / rank;      // d_in = 4096
    const long M    = (long)in_sizes[0] / K;   // 8192
    const float scale = 16.0f / (float)rank;   // alpha/rank = 2.0

    bf16* Xb = (bf16*)d_ws;
    bf16* Wb = Xb + (size_t)M * K;
    const size_t need = ((size_t)M * K + (size_t)N * K) * sizeof(bf16);
    if (ws_size < need) {
        fprintf(stderr, "kernel_launch: ws_size %zu < needed %zu\n", ws_size, need);
        return;
    }

    const long n8x = (long)M * K / 8;
    prep_fused<<<dim3((unsigned)(WXBLK + N)), dim3(256), 0, stream>>>(
        x, base, lA, lB, Xb, Wb, n8x, K, rank, scale);

    gemm_2reg<<<dim3(N / BN, (unsigned)(M / BM)), dim3(512), 0, stream>>>(
        Xb, Wb, bias, out, (int)M, N, K);
}

// Round 5
// 517.694 us; speedup vs baseline: 1.0687x; 1.0687x over previous
//
#include <hip/hip_runtime.h>
#include <hip/hip_bf16.h>
#include <cstdio>

// LoRALinear: out[M,N] = x[M,K] @ W[N,K]^T + bias, W = base + (16/8)*(lora_B @ lora_A)
// M=8192, N=4096, K=4096 (fp32 in/out; internal bf16 MFMA).
// R9: R6/R7/R8 (8-bar, deep-prefetch, 2-bar) all ~281us -> sync schedule is NOT the
// constraint. Cycle model: tile = 5300cy ~= MFMA 2480 + LDS-read 1900 + LDS-write 400
// SERIALIZED (each region: ds_read -> lgkm wait -> MFMA). Fix: register double-buffer
// fragments. Each region: MFMA on frags loaded LAST region; this region's 12 ds_reads
// prefetch next region's frags and retire under the MFMA. vmcnt ledger: 4/region issued;
// vmcnt(4) at each region end proves next slab landed (tail: 0 at NT-2.regB; tile NT-1
// needs no sync). +96 VGPR for 24 live bf16x8 frags.

using bf16   = __bf16;
using bf16x8 = __attribute__((ext_vector_type(8))) __bf16;
using f32x4  = __attribute__((ext_vector_type(4))) float;

#define BM 256
#define BN 256
#define BK 64   // two K-slabs of 32
#define WXBLK 2048

// ---------------- kernel 1: fused prep (x-convert || W-build) ----------------
__global__ __launch_bounds__(256) void prep_fused(
    const float* __restrict__ x, const float* __restrict__ base,
    const float* __restrict__ A, const float* __restrict__ Bm,
    bf16* __restrict__ Xb, bf16* __restrict__ Wb,
    long n8x, int K, int rank, float scale) {
    if (blockIdx.x < WXBLK) {
        const long stride = (long)WXBLK * 256;
        for (long i = (long)blockIdx.x * 256 + threadIdx.x; i < n8x; i += stride) {
            const float4 a = reinterpret_cast<const float4*>(x)[2 * i];
            const float4 b = reinterpret_cast<const float4*>(x)[2 * i + 1];
            bf16x8 o;
            o[0] = (bf16)a.x; o[1] = (bf16)a.y; o[2] = (bf16)a.z; o[3] = (bf16)a.w;
            o[4] = (bf16)b.x; o[5] = (bf16)b.y; o[6] = (bf16)b.z; o[7] = (bf16)b.w;
            reinterpret_cast<bf16x8*>(Xb)[i] = o;
        }
    } else {
        const int o = blockIdx.x - WXBLK;
        float br[8];
        const int rr = rank < 8 ? rank : 8;
        for (int r = 0; r < rr; ++r) br[r] = scale * Bm[(size_t)o * rank + r];

        const float* brow = base + (size_t)o * K;
        bf16*        wrow = Wb + (size_t)o * K;

        for (int c = threadIdx.x * 8; c < K; c += 256 * 8) {
            float4 s0 = *reinterpret_cast<const float4*>(brow + c);
            float4 s1 = *reinterpret_cast<const float4*>(brow + c + 4);
            if (rank == 8) {
#pragma unroll
                for (int r = 0; r < 8; ++r) {
                    const float4 a0 = *reinterpret_cast<const float4*>(A + (size_t)r * K + c);
                    const float4 a1 = *reinterpret_cast<const float4*>(A + (size_t)r * K + c + 4);
                    s0.x += br[r] * a0.x; s0.y += br[r] * a0.y;
                    s0.z += br[r] * a0.z; s0.w += br[r] * a0.w;
                    s1.x += br[r] * a1.x; s1.y += br[r] * a1.y;
                    s1.z += br[r] * a1.z; s1.w += br[r] * a1.w;
                }
            } else {
                for (int r = 0; r < rank; ++r) {
                    const float b = scale * Bm[(size_t)o * rank + r];
                    const float4 a0 = *reinterpret_cast<const float4*>(A + (size_t)r * K + c);
                    const float4 a1 = *reinterpret_cast<const float4*>(A + (size_t)r * K + c + 4);
                    s0.x += b * a0.x; s0.y += b * a0.y; s0.z += b * a0.z; s0.w += b * a0.w;
                    s1.x += b * a1.x; s1.y += b * a1.y; s1.z += b * a1.z; s1.w += b * a1.w;
                }
            }
            bf16x8 ov;
            ov[0] = (bf16)s0.x; ov[1] = (bf16)s0.y; ov[2] = (bf16)s0.z; ov[3] = (bf16)s0.w;
            ov[4] = (bf16)s1.x; ov[5] = (bf16)s1.y; ov[6] = (bf16)s1.z; ov[7] = (bf16)s1.w;
            *reinterpret_cast<bf16x8*>(wrow + c) = ov;
        }
    }
}

// ---------------- kernel 2: 256x256 reg-pipelined bf16 GEMM ----------------
// LDS per matrix: [2 buf][2 kslab][256 rows][32 elems]; slab = 16KiB, staged by
// 2 global_load_lds x 16B per thread (linear dest, source pre-swizzled c^((r>>1)&3)).
// 8 waves 2Mx4N; per-wave C 128x64. Frag sets: S0={b0,a00,a01}, S1={b1,a10,a11}.
//   regA(t): read S1 frags (cur.s1); STAGE (t+1).s1->nxt; lgkm(12); MFMA S0; vmcnt(4); bar
//   regB(t): read S0 frags of t+1 (nxt.s0); STAGE (t+2).s0->cur; lgkm(12); MFMA S1; vmcnt(4); bar
__global__ __launch_bounds__(512, 2) void gemm_rp(
    const bf16* __restrict__ Xb,    // [M,K] row-major
    const bf16* __restrict__ Wb,    // [N,K] row-major
    const float* __restrict__ bias, // [N]
    float* __restrict__ out,        // [M,N] row-major fp32
    int M, int N, int K)
{
    __shared__ __align__(16) bf16 As[2 * 2 * 256 * 32];  // 64 KiB
    __shared__ __align__(16) bf16 Bs[2 * 2 * 256 * 32];  // 64 KiB

    const int tid  = threadIdx.x;     // 0..511
    const int lane = tid & 63;
    const int wv   = tid >> 6;        // wave 0..7
    const int wm   = wv >> 2;         // 0..1
    const int wn   = wv & 3;          // 0..3

    // ---- XCD-aware bijective block swizzle (T1): nwg=512, 512%8==0 ----
    const int nbx = gridDim.x;
    const int nwg = gridDim.x * gridDim.y;
    const int orig = blockIdx.y * nbx + blockIdx.x;
    const int swz = ((nwg & 7) == 0) ? ((orig & 7) * (nwg >> 3) + (orig >> 3)) : orig;
    const int m0 = (swz / nbx) * BM;
    const int n0 = (swz % nbx) * BN;

    const int r16 = lane & 15;        // row-in-16 for frags; col for C/D
    const int q   = lane >> 4;        // quad 0..3 -> K-chunk within slab
    const int cq  = (q ^ ((r16 >> 1) & 3)) * 8;  // swizzled elem offset in 32-wide row

    // ---- staging: slot(i)=i*512+tid; row=slot>>2; src chunk c = (tid&3)^((row>>1)&3)
    const bf16* srcA[2];
    const bf16* srcB[2];
#pragma unroll
    for (int i = 0; i < 2; ++i) {
        const int slot = i * 512 + tid;
        const int row  = slot >> 2;
        const int c    = (tid & 3) ^ ((row >> 1) & 3);
        srcA[i] = Xb + (size_t)(m0 + row) * K + c * 8;
        srcB[i] = Wb + (size_t)(n0 + row) * K + c * 8;
    }
    const int dst0 = (0 * 512 + wv * 64) * 8;
    const int dst1 = (1 * 512 + wv * 64) * 8;

#define STAGE_A(buf, kh, koff)                                                        \
    do {                                                                              \
        __builtin_amdgcn_global_load_lds(                                             \
            (const __attribute__((address_space(1))) void*)(srcA[0] + (koff) + (kh) * 32), \
            (__attribute__((address_space(3))) void*)(As + (buf) * 16384 + (kh) * 8192 + dst0), \
            16, 0, 0);                                                                \
        __builtin_amdgcn_global_load_lds(                                             \
            (const __attribute__((address_space(1))) void*)(srcA[1] + (koff) + (kh) * 32), \
            (__attribute__((address_space(3))) void*)(As + (buf) * 16384 + (kh) * 8192 + dst1), \
            16, 0, 0);                                                                \
    } while (0)
#define STAGE_B(buf, kh, koff)                                                        \
    do {                                                                              \
        __builtin_amdgcn_global_load_lds(                                             \
            (const __attribute__((address_space(1))) void*)(srcB[0] + (koff) + (kh) * 32), \
            (__attribute__((address_space(3))) void*)(Bs + (buf) * 16384 + (kh) * 8192 + dst0), \
            16, 0, 0);                                                                \
        __builtin_amdgcn_global_load_lds(                                             \
            (const __attribute__((address_space(1))) void*)(srcB[1] + (koff) + (kh) * 32), \
            (__attribute__((address_space(3))) void*)(Bs + (buf) * 16384 + (kh) * 8192 + dst1), \
            16, 0, 0);                                                                \
    } while (0)

    // ---- k-invariant fragment element offsets (within a slab) ----
    int aoff[2][4], boff[4];
#pragma unroll
    for (int mh = 0; mh < 2; ++mh)
#pragma unroll
        for (int f = 0; f < 4; ++f)
            aoff[mh][f] = (wm * 128 + mh * 64 + f * 16 + r16) * 32 + cq;
#pragma unroll
    for (int f = 0; f < 4; ++f)
        boff[f] = (wn * 64 + f * 16 + r16) * 32 + cq;

    f32x4 acc[8][4] = {};
    bf16x8 b0[4], a00[4], a01[4];   // frag set S0 (slab0 of current tile)
    bf16x8 b1[4], a10[4], a11[4];   // frag set S1 (slab1 of current tile)

    const int NT = K / BK;

    // ---- prologue: stage t0 fully + t1.s0; announce t0; preload S0 frags ----
    STAGE_A(0, 0, 0);
    STAGE_B(0, 0, 0);
    STAGE_A(0, 1, 0);
    STAGE_B(0, 1, 0);
    if (NT > 1) {
        STAGE_A(1, 0, BK);
        STAGE_B(1, 0, BK);
        asm volatile("s_waitcnt vmcnt(4)" ::: "memory");   // t0 landed; t1.s0 in flight
    } else {
        asm volatile("s_waitcnt vmcnt(0)" ::: "memory");
    }
    __builtin_amdgcn_s_barrier();
    {
        const bf16* Ab = As;
        const bf16* Bb = Bs;
#pragma unroll
        for (int f = 0; f < 4; ++f) b0[f]  = *reinterpret_cast<const bf16x8*>(Bb + boff[f]);
#pragma unroll
        for (int f = 0; f < 4; ++f) a00[f] = *reinterpret_cast<const bf16x8*>(Ab + aoff[0][f]);
#pragma unroll
        for (int f = 0; f < 4; ++f) a01[f] = *reinterpret_cast<const bf16x8*>(Ab + aoff[1][f]);
    }

    for (int t = 0; t < NT; ++t) {
        const int cur   = t & 1;
        const int nxt   = cur ^ 1;
        const int koff1 = (t + 1) * BK;
        const int koff2 = (t + 2) * BK;
        const bool pre1 = (t + 1 < NT);
        const bool pre2 = (t + 2 < NT);

        // ================= region A: MFMA slab0 (S0 in regs); prefetch S1 =================
        {
            const bf16* Ab = As + cur * 16384 + 8192;
            const bf16* Bb = Bs + cur * 16384 + 8192;
#pragma unroll
            for (int f = 0; f < 4; ++f) b1[f]  = *reinterpret_cast<const bf16x8*>(Bb + boff[f]);
#pragma unroll
            for (int f = 0; f < 4; ++f) a10[f] = *reinterpret_cast<const bf16x8*>(Ab + aoff[0][f]);
#pragma unroll
            for (int f = 0; f < 4; ++f) a11[f] = *reinterpret_cast<const bf16x8*>(Ab + aoff[1][f]);
            if (pre1) { STAGE_A(nxt, 1, koff1); STAGE_B(nxt, 1, koff1); }   // (t+1).s1
            __builtin_amdgcn_sched_barrier(0);
            asm volatile("s_waitcnt lgkmcnt(12)" ::: "memory");             // S0 frags landed
            __builtin_amdgcn_sched_barrier(0);
            __builtin_amdgcn_s_setprio(1);
#pragma unroll
            for (int f = 0; f < 4; ++f)
#pragma unroll
                for (int n = 0; n < 4; ++n)
                    acc[f][n] = __builtin_amdgcn_mfma_f32_16x16x32_bf16(a00[f], b0[n], acc[f][n], 0, 0, 0);
#pragma unroll
            for (int f = 0; f < 4; ++f)
#pragma unroll
                for (int n = 0; n < 4; ++n)
                    acc[4 + f][n] = __builtin_amdgcn_mfma_f32_16x16x32_bf16(a01[f], b0[n], acc[4 + f][n], 0, 0, 0);
            __builtin_amdgcn_s_setprio(0);
            __builtin_amdgcn_sched_barrier(0);
            if (t < NT - 1) {
                // (t+1).s0 (issued t-1.regB or prologue): 4 newer ((t+1).s1) -> vmcnt(4)
                asm volatile("s_waitcnt vmcnt(4)" ::: "memory");
                __builtin_amdgcn_s_barrier();   // announce (t+1).s0; release cur.s0
            }
        }
        // ================= region B: MFMA slab1 (S1 in regs); prefetch next S0 =================
        {
            const bf16* Ab = As + nxt * 16384;
            const bf16* Bb = Bs + nxt * 16384;
            if (pre1) {
#pragma unroll
                for (int f = 0; f < 4; ++f) b0[f]  = *reinterpret_cast<const bf16x8*>(Bb + boff[f]);
#pragma unroll
                for (int f = 0; f < 4; ++f) a00[f] = *reinterpret_cast<const bf16x8*>(Ab + aoff[0][f]);
#pragma unroll
                for (int f = 0; f < 4; ++f) a01[f] = *reinterpret_cast<const bf16x8*>(Ab + aoff[1][f]);
            }
            if (pre2) { STAGE_A(cur, 0, koff2); STAGE_B(cur, 0, koff2); }   // (t+2).s0
            __builtin_amdgcn_sched_barrier(0);
            if (pre1) asm volatile("s_waitcnt lgkmcnt(12)" ::: "memory");   // S1 frags landed
            else      asm volatile("s_waitcnt lgkmcnt(0)"  ::: "memory");
            __builtin_amdgcn_sched_barrier(0);
            __builtin_amdgcn_s_setprio(1);
#pragma unroll
            for (int f = 0; f < 4; ++f)
#pragma unroll
                for (int n = 0; n < 4; ++n)
                    acc[f][n] = __builtin_amdgcn_mfma_f32_16x16x32_bf16(a10[f], b1[n], acc[f][n], 0, 0, 0);
#pragma unroll
            for (int f = 0; f < 4; ++f)
#pragma unroll
                for (int n = 0; n < 4; ++n)
                    acc[4 + f][n] = __builtin_amdgcn_mfma_f32_16x16x32_bf16(a11[f], b1[n], acc[4 + f][n], 0, 0, 0);
            __builtin_amdgcn_s_setprio(0);
            __builtin_amdgcn_sched_barrier(0);
            if (t < NT - 1) {
                // (t+1).s1 (issued t.regA): newer = (t+2).s0 if staged -> vmcnt(4) else 0
                if (t == NT - 2) asm volatile("s_waitcnt vmcnt(0)" ::: "memory");
                else             asm volatile("s_waitcnt vmcnt(4)" ::: "memory");
                __builtin_amdgcn_s_barrier();   // announce (t+1).s1; release cur.s1
            }
        }
    }

    // ---- epilogue: C/D layout col=lane&15, row=q*4+r; add bias; fp32 store ----
#pragma unroll
    for (int mf = 0; mf < 8; ++mf) {
        const int gr = m0 + wm * 128 + (mf >> 2) * 64 + (mf & 3) * 16 + q * 4;
#pragma unroll
        for (int nf = 0; nf < 4; ++nf) {
            const int gc = n0 + wn * 64 + nf * 16 + r16;
            const float bv = bias[gc];
#pragma unroll
            for (int r = 0; r < 4; ++r)
                out[(size_t)(gr + r) * N + gc] = acc[mf][nf][r] + bv;
        }
    }
#undef STAGE_A
#undef STAGE_B
}

extern "C" void kernel_launch(void* const* d_in, const int* in_sizes, int n_in,
                              void* d_out, int out_size, void* d_ws, size_t ws_size,
                              hipStream_t stream) {
    const float* x    = (const float*)d_in[0];
    const float* base = (const float*)d_in[1];
    const float* lA   = (const float*)d_in[2];
    const float* lB   = (const float*)d_in[3];
    const float* bias = (const float*)d_in[4];
    float* out = (float*)d_out;

    const int  N    = in_sizes[4];             // d_out = 4096
    const int  rank = in_sizes[3] / N;         // 8
    const int  K    = in_sizes[2] / rank;      // d_in = 4096
    const long M    = (long)in_sizes[0] / K;   // 8192
    const float scale = 16.0f / (float)rank;   // alpha/rank = 2.0

    bf16* Xb = (bf16*)d_ws;
    bf16* Wb = Xb + (size_t)M * K;
    const size_t need = ((size_t)M * K + (size_t)N * K) * sizeof(bf16);
    if (ws_size < need) {
        fprintf(stderr, "kernel_launch: ws_size %zu < needed %zu\n", ws_size, need);
        return;
    }

    const long n8x = (long)M * K / 8;
    prep_fused<<<dim3((unsigned)(WXBLK + N)), dim3(256), 0, stream>>>(
        x, base, lA, lB, Xb, Wb, n8x, K, rank, scale);

    gemm_rp<<<dim3(N / BN, (unsigned)(M / BM)), dim3(512), 0, stream>>>(
        Xb, Wb, bias, out, (int)M, N, K);
}